// Round 2
// baseline (27168.079 us; speedup 1.0000x reference)
//
#include <hip/hip_runtime.h>
#include <cstdint>
#include <cstddef>

#define LI 64
#define NB 32
#define E  128
#define ENC 128
#define D2 128
#define VOC 32000
#define CIN 384   // 2*ENC + E
#define G5 640    // 5*D2
#define G4 512    // 4*ENC
#define NCK 256   // vocab chunks
#define VPC 125   // vocab per chunk
#define TPB 640
#define NBLK 256

// ws layout (float offsets)
#define OFF_XF    0
#define OFF_XB    1048576
#define OFF_HENC  2097152
#define OFF_HX    2621440
#define OFF_VPRE  3932160   // 2 x 1310720
#define OFF_SC    6553600   // [s0 c0 s1 c1] each 262144
#define OFF_LG    7602176   // 2 x 1024000
#define OFF_CKV   9650176   // 2 x 8192
#define OFF_CKI   9666560   // 2 x 8192 (ints)
#define OFF_FLAGS 9682944   // 256 ints

// flag indices
#define F_EMBED 0
#define F_ENC   1
#define F_HX    2
#define F_ROW   3    // 64
#define F_POST  67   // 64

__device__ __forceinline__ float sigf(float x) { return 1.0f / (1.0f + __expf(-x)); }
__device__ __forceinline__ float tanhf_(float x) {
  float e = __expf(2.0f * x);
  return 1.0f - 2.0f / (e + 1.0f);
}

__device__ __forceinline__ void fwait(int* f, int tgt) {
  if (threadIdx.x == 0) {
    while (__hip_atomic_load(f, __ATOMIC_ACQUIRE, __HIP_MEMORY_SCOPE_AGENT) < tgt)
      __builtin_amdgcn_s_sleep(2);
  }
  __syncthreads();
}
__device__ __forceinline__ void fadd(int* f) {
  __syncthreads();
  if (threadIdx.x == 0)
    (void)__hip_atomic_fetch_add(f, 1, __ATOMIC_RELEASE, __HIP_MEMORY_SCOPE_AGENT);
}

// block-uniform call; internal barriers are all-thread
__device__ void softmax_write(int r, int b, const float* __restrict__ LG,
                              const float* __restrict__ CKV,
                              float* __restrict__ out, float* s_red)
{
  int tid = threadIdx.x;
  const float* lgr  = LG + (size_t)(r & 1) * 1024000 + (size_t)b * VOC;
  const float* ckvr = CKV + (size_t)(r & 1) * 8192 + b * NCK;
  if (tid < 256) s_red[tid] = ckvr[tid];
  __syncthreads();
  for (int off = 128; off > 0; off >>= 1) {
    if (tid < off) s_red[tid] = fmaxf(s_red[tid], s_red[tid + off]);
    __syncthreads();
  }
  float M = s_red[0];
  __syncthreads();
  float S = 0.0f;
  if (tid < 256) {
    for (int k = 0; k < VPC; ++k) S += __expf(lgr[tid + 256 * k] - M);
    s_red[tid] = S;
  }
  __syncthreads();
  for (int off = 128; off > 0; off >>= 1) {
    if (tid < off) s_red[tid] += s_red[tid + off];
    __syncthreads();
  }
  float rinv = 1.0f / s_red[0];
  float* o = out + ((size_t)r * NB + b) * VOC;
  for (int v = tid; v < VOC; v += TPB)
    o[v] = __expf(lgr[v] - M) * rinv;
  __syncthreads();
}

__global__ __launch_bounds__(TPB) void mega(
    const int* __restrict__ x, const float* __restrict__ embed,
    const float* __restrict__ Wihf, const float* __restrict__ Whhf,
    const float* __restrict__ bihf, const float* __restrict__ bhhf,
    const float* __restrict__ Wihb, const float* __restrict__ Whhb,
    const float* __restrict__ bihb, const float* __restrict__ bhhb,
    const float* __restrict__ Wx, const float* __restrict__ bx,
    const float* __restrict__ Ws, const float* __restrict__ bs,
    const float* __restrict__ logW, const float* __restrict__ logb,
    float* __restrict__ ws, int* __restrict__ F, float* __restrict__ out)
{
  // 96 KB static LDS: forces exactly 1 block/CU (grid 256 = 256 CUs, all co-resident)
  __shared__ float LB[24576];
  float* s_embs = LB;            // 1024  (phase A)
  float* s_hh   = LB;            // 2048  (phase C)
  float* s_zbE  = LB;            // 512   (encoder z)
  float* s_hb   = LB + 512;      // 128   (encoder h)
  float* s_zb   = LB;            // 640   (rec z)
  float* s_sb   = LB + 640;      // 128   (rec s)
  float* s_yb   = LB + 768;      // 128   (rec y embed)
  int*   s_tok  = (int*)(LB + 896);
  float* s_red  = LB;            // 256   (softmax)
  float* s_sr   = LB;            // 1024  (post vpre staging)

  float* Xf   = ws + OFF_XF;
  float* Xb   = ws + OFF_XB;
  float* henc = ws + OFF_HENC;
  float* Hx   = ws + OFF_HX;
  float* Vpre = ws + OFF_VPRE;
  float* SC   = ws + OFF_SC;
  float* LG   = ws + OFF_LG;
  float* CKV  = ws + OFF_CKV;
  int*   CKI  = (int*)(ws + OFF_CKI);

  int bid = blockIdx.x, tid = threadIdx.x;

  // ---------------- Phase A: embedding gather + encoder input precompute ----
  {
    int t = bid >> 2, bg = (bid & 3) * 8;
    for (int idx = tid; idx < 8 * E; idx += TPB) {
      int bb = idx >> 7, e = idx & 127;
      int tok = x[t * NB + bg + bb];
      s_embs[bb * E + e] = embed[(size_t)tok * E + e];
    }
    __syncthreads();
    if (tid < G4) {
      for (int dir = 0; dir < 2; ++dir) {
        const float4* wrow = (const float4*)((dir ? Wihb : Wihf) + (size_t)tid * E);
        float bias = dir ? (bihb[tid] + bhhb[tid]) : (bihf[tid] + bhhf[tid]);
        float acc[8];
        #pragma unroll
        for (int r = 0; r < 8; ++r) acc[r] = bias;
        for (int q = 0; q < E / 4; ++q) {
          float4 w = wrow[q];
          #pragma unroll
          for (int r = 0; r < 8; ++r) {
            float4 e4 = ((const float4*)(s_embs + r * E))[q];
            acc[r] += w.x * e4.x + w.y * e4.y + w.z * e4.z + w.w * e4.w;
          }
        }
        float* X = dir ? Xb : Xf;
        #pragma unroll
        for (int r = 0; r < 8; ++r)
          X[(size_t)(t * NB + bg + r) * G4 + tid] = acc[r];
      }
    }
    fadd(&F[F_EMBED]);
  }

  // ---------------- Phase B: bidirectional encoder LSTM (blocks 0..63) ------
  if (bid < 64) {
    fwait(&F[F_EMBED], NBLK);
    int b = bid >> 1, dir = bid & 1;
    const float* X   = dir ? Xb : Xf;
    const float* Whh = dir ? Whhb : Whhf;
    float4 w[ENC / 4];
    if (tid < G4) {
      const float4* wrow = (const float4*)(Whh + (size_t)tid * ENC);
      #pragma unroll
      for (int q = 0; q < ENC / 4; ++q) w[q] = wrow[q];
    }
    if (tid < ENC / 4) ((float4*)s_hb)[tid] = make_float4(0.f, 0.f, 0.f, 0.f);
    float c = 0.0f;
    __syncthreads();
    for (int st = 0; st < LI; ++st) {
      int t = dir ? (LI - 1 - st) : st;
      if (tid < G4) {
        float a0 = X[(size_t)(t * NB + b) * G4 + tid], a1 = 0.f, a2 = 0.f, a3 = 0.f;
        const float4* hb4 = (const float4*)s_hb;
        #pragma unroll
        for (int q = 0; q < ENC / 4; q += 4) {
          float4 h0 = hb4[q], h1 = hb4[q + 1], h2 = hb4[q + 2], h3 = hb4[q + 3];
          a0 += w[q].x * h0.x + w[q].y * h0.y + w[q].z * h0.z + w[q].w * h0.w;
          a1 += w[q+1].x * h1.x + w[q+1].y * h1.y + w[q+1].z * h1.z + w[q+1].w * h1.w;
          a2 += w[q+2].x * h2.x + w[q+2].y * h2.y + w[q+2].z * h2.z + w[q+2].w * h2.w;
          a3 += w[q+3].x * h3.x + w[q+3].y * h3.y + w[q+3].z * h3.z + w[q+3].w * h3.w;
        }
        s_zbE[tid] = (a0 + a1) + (a2 + a3);
      }
      __syncthreads();
      if (tid < ENC) {
        float zi = s_zbE[tid], zf = s_zbE[ENC + tid],
              zg = s_zbE[2 * ENC + tid], zo = s_zbE[3 * ENC + tid];
        c = sigf(zf) * c + sigf(zi) * tanhf_(zg);
        float h = sigf(zo) * tanhf_(c);
        s_hb[tid] = h;
        henc[(size_t)(t * NB + b) * (2 * ENC) + dir * ENC + tid] = h;
      }
      __syncthreads();
    }
    fadd(&F[F_ENC]);
  }

  // ---------------- Phase C: Hx = henc @ Wx_h.T + bx + bs ; seed Vpre[0] ----
  {
    fwait(&F[F_ENC], 64);
    int rowbase = bid * 8;
    for (int idx = tid; idx < 8 * 2 * ENC; idx += TPB) {
      int rr = idx >> 8, k = idx & 255;
      s_hh[rr * 256 + k] = henc[(size_t)(rowbase + rr) * (2 * ENC) + k];
    }
    __syncthreads();
    const float4* wrow = (const float4*)(Wx + (size_t)tid * CIN + E);
    float bias = bx[tid] + bs[tid];
    float acc[8];
    #pragma unroll
    for (int r = 0; r < 8; ++r) acc[r] = bias;
    for (int q = 0; q < (2 * ENC) / 4; ++q) {
      float4 w = wrow[q];
      #pragma unroll
      for (int r = 0; r < 8; ++r) {
        float4 h4 = ((const float4*)(s_hh + r * 256))[q];
        acc[r] += w.x * h4.x + w.y * h4.y + w.z * h4.z + w.w * h4.w;
      }
    }
    #pragma unroll
    for (int r = 0; r < 8; ++r) {
      size_t o = (size_t)(rowbase + r) * G5 + tid;
      Hx[o] = acc[r];
      Vpre[o] = acc[r];   // parity-0 buffer, row 0 (s_ver = 0)
    }
    fadd(&F[F_HX]);
  }

  // ---------------- Decode rows -------------------------------------------
  for (int i = 0; i < 64; ++i) {
    float* scur  = SC + (size_t)(i & 1) * 524288;
    float* ccur  = scur + 262144;
    float* cprev = SC + (size_t)((i + 1) & 1) * 524288 + 262144;
    const float* Vp = Vpre + (size_t)(i & 1) * 1310720;

    if (bid < 32) {
      // -------- recurrence for batch b = bid --------
      if (i == 0) fwait(&F[F_HX], NBLK); else fwait(&F[F_POST + i - 1], NBLK);
      int b = bid;
      float yxr = 0.0f;
      if (i > 0) {
        const float* ckv = CKV + (size_t)((i + 1) & 1) * 8192;
        const int*   cki = CKI + (size_t)((i + 1) & 1) * 8192;
        if (tid < 64) {
          float bv = -3.4e38f; int bi = 0x7fffffff;
          #pragma unroll
          for (int cc = 0; cc < 4; ++cc) {
            int c = tid + 64 * cc;
            float v = ckv[b * NCK + c];
            int  id = cki[b * NCK + c];
            if (v > bv || (v == bv && id < bi)) { bv = v; bi = id; }
          }
          #pragma unroll
          for (int off = 1; off < 64; off <<= 1) {
            float ov = __shfl_xor(bv, off);
            int   oi = __shfl_xor(bi, off);
            if (ov > bv || (ov == bv && oi < bi)) { bv = ov; bi = oi; }
          }
          if (tid == 0) *s_tok = bi;
        }
        __syncthreads();
        int tok = *s_tok;
        if (tid < E) s_yb[tid] = embed[(size_t)tok * E + tid];
        __syncthreads();
        const float4* wy = (const float4*)(Wx + (size_t)tid * CIN);
        const float4* y4 = (const float4*)s_yb;
        float a = 0.0f;
        #pragma unroll
        for (int q = 0; q < E / 4; ++q) {
          float4 w = wy[q], y = y4[q];
          a += w.x * y.x + w.y * y.y + w.z * y.z + w.w * y.w;
        }
        yxr = a;
      }
      float4 w[D2 / 4];
      {
        const float4* wrow = (const float4*)(Ws + (size_t)tid * (2 * D2));
        #pragma unroll
        for (int q = 0; q < D2 / 4; ++q) w[q] = wrow[q];
      }
      if (tid < D2 / 4) ((float4*)s_sb)[tid] = make_float4(0.f, 0.f, 0.f, 0.f);
      float chor = 0.0f;
      __syncthreads();
      float vnext = Vp[(size_t)(0 * NB + b) * G5 + tid];
      float cvn = (tid < D2) ? cprev[(size_t)(0 * NB + b) * D2 + tid] : 0.0f;
      for (int j = 0; j < LI; ++j) {
        float a0 = yxr + vnext, a1 = 0.f, a2 = 0.f, a3 = 0.f;
        if (j < LI - 1) vnext = Vp[(size_t)((j + 1) * NB + b) * G5 + tid];
        const float4* sb4 = (const float4*)s_sb;
        #pragma unroll
        for (int q = 0; q < D2 / 4; q += 4) {
          float4 s0 = sb4[q], s1 = sb4[q + 1], s2 = sb4[q + 2], s3 = sb4[q + 3];
          a0 += w[q].x * s0.x + w[q].y * s0.y + w[q].z * s0.z + w[q].w * s0.w;
          a1 += w[q+1].x * s1.x + w[q+1].y * s1.y + w[q+1].z * s1.z + w[q+1].w * s1.w;
          a2 += w[q+2].x * s2.x + w[q+2].y * s2.y + w[q+2].z * s2.z + w[q+2].w * s2.w;
          a3 += w[q+3].x * s3.x + w[q+3].y * s3.y + w[q+3].z * s3.z + w[q+3].w * s3.w;
        }
        s_zb[tid] = (a0 + a1) + (a2 + a3);
        __syncthreads();
        if (tid < D2) {
          float zi = s_zb[tid], zf = s_zb[D2 + tid], zo = s_zb[2 * D2 + tid],
                zl = s_zb[3 * D2 + tid], zg = s_zb[4 * D2 + tid];
          float cv = cvn;
          if (j < LI - 1) cvn = cprev[(size_t)((j + 1) * NB + b) * D2 + tid];
          float ii = sigf(zi), ff = sigf(zf), oo = sigf(zo), ll = sigf(zl);
          float gg = tanhf_(zg);
          float c = ff * (ll * chor + (1.0f - ll) * cv) + ii * gg;
          float s = oo * tanhf_(c);
          chor = c;
          s_sb[tid] = s;
          size_t o = (size_t)(j * NB + b) * D2 + tid;
          ccur[o] = c;
          scur[o] = s;
        }
        __syncthreads();
      }
      fadd(&F[F_ROW + i]);
    } else if (bid < 64) {
      // -------- softmax + output write of row i-1 (hidden under recurrence) --
      if (i >= 1) {
        fwait(&F[F_POST + i - 1], NBLK);
        softmax_write(i - 1, bid - 32, LG, CKV, out, s_red);
      }
    }

    // -------- post phase: logits(i) + Vpre(i+1), all 256 blocks -------------
    fwait(&F[F_ROW + i], 32);
    for (int idx = tid; idx < 8 * D2; idx += TPB) {
      int rr = idx >> 7, k = idx & 127;
      s_sr[rr * D2 + k] = scur[(size_t)(bid * 8 + rr) * D2 + k];
    }
    __syncthreads();
    if (tid < 256) {
      // logits chunk `bid`
      int b = tid >> 3, r = tid & 7;
      const float4* sp = (const float4*)(scur + (size_t)(63 * NB + b) * D2 + r * 16);
      float4 s0 = sp[0], s1 = sp[1], s2 = sp[2], s3 = sp[3];
      float bm = -3.4e38f; int bmi = 0;
      int v0 = bid * VPC;
      float* lgcur = LG + (size_t)(i & 1) * 1024000;
      for (int k = 0; k < VPC; ++k) {
        int v = v0 + k;
        const float4* lw = (const float4*)(logW + (size_t)v * D2 + r * 16);
        float4 a0 = lw[0], a1 = lw[1], a2 = lw[2], a3 = lw[3];
        float sum = a0.x*s0.x + a0.y*s0.y + a0.z*s0.z + a0.w*s0.w
                  + a1.x*s1.x + a1.y*s1.y + a1.z*s1.z + a1.w*s1.w
                  + a2.x*s2.x + a2.y*s2.y + a2.z*s2.z + a2.w*s2.w
                  + a3.x*s3.x + a3.y*s3.y + a3.z*s3.z + a3.w*s3.w;
        sum += __shfl_xor(sum, 1);
        sum += __shfl_xor(sum, 2);
        sum += __shfl_xor(sum, 4);
        if (r == 0) {
          float lgv = sum + logb[v];
          lgcur[(size_t)b * VOC + v] = lgv;
          if (lgv > bm) { bm = lgv; bmi = v; }
        }
      }
      if (r == 0) {
        CKV[(size_t)(i & 1) * 8192 + b * NCK + bid] = bm;
        CKI[(size_t)(i & 1) * 8192 + b * NCK + bid] = bmi;
      }
    } else if (tid < 512 && i < 63) {
      // Vpre(i+1) rows [bid*8, bid*8+8)
      int t2 = tid - 256;
      float* Vnxt = Vpre + (size_t)((i + 1) & 1) * 1310720;
      int rowbase = bid * 8;
      for (int gd = t2; gd < G5; gd += 256) {
        const float4* wrow = (const float4*)(Ws + (size_t)gd * (2 * D2) + D2);
        float acc[8];
        #pragma unroll
        for (int rr = 0; rr < 8; ++rr) acc[rr] = 0.0f;
        for (int q = 0; q < D2 / 4; ++q) {
          float4 ww = wrow[q];
          #pragma unroll
          for (int rr = 0; rr < 8; ++rr) {
            float4 s4 = ((const float4*)(s_sr + rr * D2))[q];
            acc[rr] += ww.x * s4.x + ww.y * s4.y + ww.z * s4.z + ww.w * s4.w;
          }
        }
        #pragma unroll
        for (int rr = 0; rr < 8; ++rr) {
          size_t o = (size_t)(rowbase + rr) * G5 + gd;
          Vnxt[o] = Hx[o] + acc[rr];
        }
      }
    }
    fadd(&F[F_POST + i]);
  }

  // ---------------- final softmax (row 63) ---------------------------------
  if (bid >= 32 && bid < 64) {
    fwait(&F[F_POST + 63], NBLK);
    softmax_write(63, bid - 32, LG, CKV, out, s_red);
  }
}

// ---------------------------------------------------------------------------
extern "C" void kernel_launch(void* const* d_in, const int* in_sizes, int n_in,
                              void* d_out, int out_size, void* d_ws, size_t ws_size,
                              hipStream_t stream)
{
  (void)in_sizes; (void)n_in; (void)out_size; (void)ws_size;
  const int*   x     = (const int*)d_in[0];
  const float* embed = (const float*)d_in[1];
  const float* Wihf  = (const float*)d_in[2];
  const float* Whhf  = (const float*)d_in[3];
  const float* bihf  = (const float*)d_in[4];
  const float* bhhf  = (const float*)d_in[5];
  const float* Wihb  = (const float*)d_in[6];
  const float* Whhb  = (const float*)d_in[7];
  const float* bihb  = (const float*)d_in[8];
  const float* bhhb  = (const float*)d_in[9];
  const float* Wx    = (const float*)d_in[10];
  const float* bx    = (const float*)d_in[11];
  const float* Ws    = (const float*)d_in[12];
  const float* bs    = (const float*)d_in[13];
  const float* logW  = (const float*)d_in[14];
  const float* logb  = (const float*)d_in[15];
  float* out = (float*)d_out;
  float* w   = (float*)d_ws;
  int* flags = (int*)(w + OFF_FLAGS);

  // zero sync flags and the row(-1) c buffer (c1 = SC + 3*262144)
  hipMemsetAsync(flags, 0, 256 * sizeof(int), stream);
  hipMemsetAsync(w + OFF_SC + 3 * 262144, 0, 262144 * sizeof(float), stream);

  mega<<<NBLK, TPB, 0, stream>>>(x, embed, Wihf, Whhf, bihf, bhhf,
                                 Wihb, Whhb, bihb, bhhb,
                                 Wx, bx, Ws, bs, logW, logb,
                                 w, flags, out);
}